// Round 4
// baseline (975.202 us; speedup 1.0000x reference)
//
#include <hip/hip_runtime.h>
#include <math.h>

// VQ-VAE EMA vector quantizer, MI355X. Round 4: round-3 design with the
// workspace-layout bug fixed (xconv is 32MB: hi+lo splits of 32768x256 f16).
// 32x32x16 MFMA + global_load_lds staging from pre-swizzled operand images.
// N=32768 rows, D=256, K=8192.

#define KC 8192
#define DD 256
#define NV 32768

typedef _Float16 f16;
typedef _Float16 f16x8 __attribute__((ext_vector_type(8)));
typedef _Float16 f16x4 __attribute__((ext_vector_type(4)));
typedef float f32x16 __attribute__((ext_vector_type(16)));

__device__ inline void load_lds16(const void* g, void* l) {
    __builtin_amdgcn_global_load_lds(
        (const __attribute__((address_space(1))) unsigned int*)g,
        (__attribute__((address_space(3))) unsigned int*)l, 16, 0, 0);
}

// ---------- x NCHW fp32 -> xconv swizzled hi/lo f16 tile images + sum(x^2) ----------
// xconv layout: [tile(n>>7)][kt(0..8)][hl][R*32 + (q^((R>>1)&3))*8], 8192 f16 per (tile,kt).
__global__ __launch_bounds__(256, 2) void k_convert_x(
    const float* __restrict__ x, f16* __restrict__ xconv, float* __restrict__ lossAcc) {
    __shared__ float xs[256][68];
    __shared__ float red[4];
    const int t = threadIdx.x;
    const int n0 = blockIdx.x * 64;
    const int b = n0 >> 10;
    const int h0 = (n0 >> 5) & 31;
    {
        const int p = t >> 7, tt = t & 127;
        const int wq = (tt & 7) * 4, d0 = tt >> 3;
        const float* src = x + (size_t)b * 262144 + (size_t)(h0 + p) * 32 + wq;
        float s2 = 0.f;
        #pragma unroll
        for (int i = 0; i < 16; ++i) {
            int d = d0 + i * 16;
            float4 v = *(const float4*)(src + (size_t)d * 1024);
            *(float4*)&xs[d][p * 32 + wq] = v;
            s2 += v.x * v.x + v.y * v.y + v.z * v.z + v.w * v.w;
        }
        for (int off = 32; off > 0; off >>= 1) s2 += __shfl_xor(s2, off);
        if ((t & 63) == 0) red[t >> 6] = s2;
    }
    __syncthreads();
    if (t == 0) atomicAdd(&lossAcc[1], red[0] + red[1] + red[2] + red[3]);
    {
        const int tile = blockIdx.x >> 1;
        const int rhalf = (blockIdx.x & 1) * 64;
        const int Rl = t >> 2, q = t & 3;
        const int R = rhalf + Rl;
        const int p = q ^ ((R >> 1) & 3);
        #pragma unroll
        for (int kt = 0; kt < 8; ++kt) {
            f16x8 hv, lv;
            #pragma unroll
            for (int j = 0; j < 8; ++j) {
                float v = xs[kt * 32 + q * 8 + j][Rl];
                f16 h = (f16)v;
                hv[j] = h; lv[j] = (f16)(v - (float)h);
            }
            size_t base = ((size_t)(tile * 8 + kt)) << 13;
            *(f16x8*)&xconv[base + R * 32 + p * 8] = hv;
            *(f16x8*)&xconv[base + 4096 + R * 32 + p * 8] = lv;
        }
    }
}

// ---------- embed fp32 [d][k] -> econv swizzled hi/lo f16 tile images ----------
// econv layout: [cb(k>>7)][kt][hl][c*32 + (q^((c>>1)&3))*8], 8192 f16 per (cb,kt).
__global__ void k_convert_e(const float* __restrict__ embed, f16* __restrict__ econv) {
    __shared__ float es[32][132];
    const int bx = blockIdx.x;
    const int cb = bx >> 3, kt = bx & 7;
    const int d0 = kt * 32, k0 = cb * 128;
    const int t = threadIdx.x;
    #pragma unroll
    for (int i = 0; i < 4; ++i) {
        int d = i * 8 + (t >> 5);
        int k = (t & 31) * 4;
        float4 v = *(const float4*)&embed[(size_t)(d0 + d) * KC + k0 + k];
        es[d][k] = v.x; es[d][k + 1] = v.y; es[d][k + 2] = v.z; es[d][k + 3] = v.w;
    }
    __syncthreads();
    const int c = t >> 1, hl = t & 1;
    const int s = (c >> 1) & 3;
    size_t base = (((size_t)(cb * 8 + kt)) << 13) + hl * 4096;
    #pragma unroll
    for (int q = 0; q < 4; ++q) {
        f16x8 ov;
        #pragma unroll
        for (int j = 0; j < 8; ++j) {
            float v = es[q * 8 + j][c];
            f16 h = (f16)v;
            ov[j] = hl ? (f16)(v - (float)h) : h;
        }
        *(f16x8*)&econv[base + c * 32 + (q ^ s) * 8] = ov;
    }
}

// ---------- enorm[k] = sum_d embed[d,k]^2 (exact fp32) ----------
__global__ void k_enorm(const float* __restrict__ embed, float* __restrict__ enorm) {
    int k = blockIdx.x * 256 + threadIdx.x;
    float s = 0.f;
    for (int d = 0; d < DD; ++d) { float v = embed[(size_t)d * KC + k]; s += v * v; }
    enorm[k] = s;
}

// ---------- MFMA distance GEMM + argmin. 128x128 block, 4 waves 2x2 of 64x64. ----------
__global__ __launch_bounds__(256, 3) void k_argmin_mfma(
    const f16* __restrict__ xconv, const f16* __restrict__ econv,
    const float* __restrict__ enorm, unsigned long long* __restrict__ rowmin) {
    __shared__ f16 stage[16384];   // 32KB: A-hi | A-lo | B-hi | B-lo (8KB each)
    __shared__ float en_s[128];
    __shared__ float mval[128][2];
    __shared__ int   midx[128][2];
    const int t = threadIdx.x;
    const int bx = blockIdx.x, by = blockIdx.y;
    const int lane = t & 63, wave = t >> 6;
    const int wr = wave >> 1, wc = wave & 1;
    const int l31 = lane & 31, half = lane >> 5;
    if (t < 128) en_s[t] = enorm[by * 128 + t];

    f32x16 acc[2][2];
    #pragma unroll
    for (int i = 0; i < 2; ++i)
        #pragma unroll
        for (int j = 0; j < 2; ++j)
            #pragma unroll
            for (int r = 0; r < 16; ++r) acc[i][j][r] = 0.f;

    // DMA sources: wave 0 -> A-hi, 1 -> A-lo, 2 -> B-hi, 3 -> B-lo
    const char* xtile = (const char*)xconv + ((size_t)bx * 8) * 16384;
    const char* etile = (const char*)econv + ((size_t)by * 8) * 16384;
    const char* srcbase = (wave < 2) ? (xtile + wave * 8192) : (etile + (wave - 2) * 8192);
    f16* dstbase = stage + wave * 4096;

    // fragment read offsets (f16 elements), xor-swizzled
    int aoff[2][2], boff[2][2];
    #pragma unroll
    for (int i = 0; i < 2; ++i) {
        int R = wr * 64 + i * 32 + l31;
        int sA = (R >> 1) & 3;
        #pragma unroll
        for (int kk = 0; kk < 2; ++kk)
            aoff[i][kk] = R * 32 + (((kk << 1) | half) ^ sA) * 8;
    }
    #pragma unroll
    for (int j = 0; j < 2; ++j) {
        int C = wc * 64 + j * 32 + l31;
        int sB = (C >> 1) & 3;
        #pragma unroll
        for (int kk = 0; kk < 2; ++kk)
            boff[j][kk] = C * 32 + (((kk << 1) | half) ^ sB) * 8;
    }

    for (int kt = 0; kt < 8; ++kt) {
        __syncthreads();
        const char* src = srcbase + (size_t)kt * 16384;
        #pragma unroll
        for (int s = 0; s < 8; ++s)
            load_lds16(src + s * 1024 + lane * 16, dstbase + s * 512);
        __syncthreads();

        f16x8 a0[2][2], a1[2][2], bh[2][2], bl[2][2];
        #pragma unroll
        for (int i = 0; i < 2; ++i)
            #pragma unroll
            for (int kk = 0; kk < 2; ++kk) {
                a0[i][kk] = *(const f16x8*)&stage[aoff[i][kk]];
                a1[i][kk] = *(const f16x8*)&stage[4096 + aoff[i][kk]];
            }
        #pragma unroll
        for (int j = 0; j < 2; ++j)
            #pragma unroll
            for (int kk = 0; kk < 2; ++kk) {
                bh[j][kk] = *(const f16x8*)&stage[8192 + boff[j][kk]];
                bl[j][kk] = *(const f16x8*)&stage[12288 + boff[j][kk]];
            }
        #pragma unroll
        for (int kk = 0; kk < 2; ++kk)
            #pragma unroll
            for (int i = 0; i < 2; ++i)
                #pragma unroll
                for (int j = 0; j < 2; ++j) {
                    acc[i][j] = __builtin_amdgcn_mfma_f32_32x32x16_f16(a0[i][kk], bh[j][kk], acc[i][j], 0, 0, 0);
                    acc[i][j] = __builtin_amdgcn_mfma_f32_32x32x16_f16(a0[i][kk], bl[j][kk], acc[i][j], 0, 0, 0);
                    acc[i][j] = __builtin_amdgcn_mfma_f32_32x32x16_f16(a1[i][kk], bh[j][kk], acc[i][j], 0, 0, 0);
                }
    }

    // argmin epilogue: C/D layout col=lane&31, row=(r&3)+8*(r>>2)+4*half (m74/m101)
    const float en0 = en_s[wc * 64 + l31];
    const float en1 = en_s[wc * 64 + 32 + l31];
    #pragma unroll
    for (int i = 0; i < 2; ++i) {
        #pragma unroll
        for (int r = 0; r < 16; ++r) {
            float d0 = en0 - 2.f * acc[i][0][r];
            float d1 = en1 - 2.f * acc[i][1][r];
            float v = d0; int ii = by * 128 + wc * 64 + l31;
            if (d1 < d0) { v = d1; ii += 32; }
            #pragma unroll
            for (int off = 1; off < 32; off <<= 1) {
                float v2 = __shfl_xor(v, off);
                int i2 = __shfl_xor(ii, off);
                if (v2 < v || (v2 == v && i2 < ii)) { v = v2; ii = i2; }
            }
            if (l31 == 0) {
                int row = wr * 64 + i * 32 + (r & 3) + 8 * (r >> 2) + 4 * half;
                mval[row][wc] = v; midx[row][wc] = ii;
            }
        }
    }
    __syncthreads();
    if (t < 128) {
        float v0 = mval[t][0], v1 = mval[t][1];
        int i0 = midx[t][0], i1 = midx[t][1];
        if (v1 < v0 || (v1 == v0 && i1 < i0)) { v0 = v1; i0 = i1; }
        unsigned int u = __float_as_uint(v0);
        u = (u & 0x80000000u) ? ~u : (u | 0x80000000u);
        unsigned long long key = ((unsigned long long)u << 32) | (unsigned int)i0;
        atomicMin(rowmin + bx * 128 + t, key);
    }
}

// ---------- decode rowmin -> idx, histogram, loss sum ----------
__global__ void k_finalize(const unsigned long long* __restrict__ rowmin,
                           int* __restrict__ idx, int* __restrict__ cnt,
                           float* __restrict__ lossAcc) {
    __shared__ float red[4];
    int t = threadIdx.x;
    int n = blockIdx.x * 256 + t;
    unsigned long long p = rowmin[n];
    unsigned int u = (unsigned int)(p >> 32);
    unsigned int u2 = (u & 0x80000000u) ? (u ^ 0x80000000u) : ~u;
    float v = __uint_as_float(u2);
    int i = (int)(unsigned int)(p & 0xFFFFFFFFu);
    idx[n] = i;
    atomicAdd(&cnt[i], 1);
    for (int off = 32; off > 0; off >>= 1) v += __shfl_xor(v, off);
    if ((t & 63) == 0) red[t >> 6] = v;
    __syncthreads();
    if (t == 0) atomicAdd(&lossAcc[0], red[0] + red[1] + red[2] + red[3]);
}

// ---------- single-block stats ----------
__global__ void k_stats(const int* __restrict__ cnt, const float* __restrict__ cluster_size,
                        const float* __restrict__ lossAcc,
                        float* __restrict__ out_ncs, float* __restrict__ out_loss,
                        float* __restrict__ out_perp,
                        float* __restrict__ smoothed, int* __restrict__ offsets) {
    __shared__ float rn[256], rp[256];
    __shared__ int rc[256];
    __shared__ int base_s[256];
    int t = threadIdx.x;
    float s_n = 0.f, s_pl = 0.f;
    int s_c = 0;
    float ncs_loc[32];
    #pragma unroll
    for (int i = 0; i < 32; ++i) {
        int k = t * 32 + i;
        int ci = cnt[k];
        float c = (float)ci;
        float ncs = cluster_size[k] * 0.99f + 0.01f * c;
        out_ncs[k] = ncs;
        ncs_loc[i] = ncs;
        s_n += ncs;
        float p = c * (1.0f / 32768.0f);
        s_pl += p * logf(p + 1e-10f);
        s_c += ci;
    }
    rn[t] = s_n; rp[t] = s_pl; rc[t] = s_c;
    for (int off = 128; off > 0; off >>= 1) {
        __syncthreads();
        if (t < off) { rn[t] += rn[t + off]; rp[t] += rp[t + off]; }
    }
    __syncthreads();
    float ntot = rn[0];
    if (t == 0) {
        out_loss[0] = 0.25f * (lossAcc[0] + lossAcc[1]) * (1.0f / 8388608.0f);
        out_perp[0] = expf(-rp[0]);
    }
    #pragma unroll
    for (int i = 0; i < 32; ++i) {
        int k = t * 32 + i;
        float ncs = ncs_loc[i];
        smoothed[k] = ntot * (ncs + 1e-5f) / (ntot + ncs * 1e-5f);
    }
    __syncthreads();
    if (t == 0) {
        int run = 0;
        for (int q = 0; q < 256; ++q) { base_s[q] = run; run += rc[q]; }
    }
    __syncthreads();
    int run = base_s[t];
    #pragma unroll
    for (int i = 0; i < 32; ++i) {
        int k = t * 32 + i;
        offsets[k] = run;
        run += cnt[k];
    }
}

// ---------- counting-sort scatter ----------
__global__ void k_scatter(const int* __restrict__ idx, const int* __restrict__ offsets,
                          int* __restrict__ cursor, int* __restrict__ order) {
    int n = blockIdx.x * 256 + threadIdx.x;
    int k = idx[n];
    int pos = offsets[k] + atomicAdd(&cursor[k], 1);
    order[pos] = n;
}

// ---------- dwT[k][d] (f16) = segment_sum of x, reading swizzled xconv ----------
__global__ void k_dw(const int* __restrict__ cnt, const int* __restrict__ offsets,
                     const int* __restrict__ order, const f16* __restrict__ xconv,
                     f16* __restrict__ dwT) {
    int k = blockIdx.x;
    int t = threadIdx.x;
    int c = cnt[k], base = offsets[k];
    int kt = t >> 5, q = (t >> 3) & 3, j = t & 7;
    float s = 0.f;
    for (int i = 0; i < c; ++i) {
        int n = order[base + i];
        int tile = n >> 7, R = n & 127;
        int p = q ^ ((R >> 1) & 3);
        size_t off = (((size_t)(tile * 8 + kt)) << 13) + R * 32 + p * 8 + j;
        s += (float)xconv[off] + (float)xconv[off + 4096];
    }
    dwT[(size_t)k * DD + t] = (f16)s;
}

// ---------- new_ema_embed / new_embed ----------
__global__ void k_update_embed(const f16* __restrict__ dwT, const float* __restrict__ ema_embed,
                               const float* __restrict__ smoothed,
                               float* __restrict__ out_embed, float* __restrict__ out_ema) {
    __shared__ float tile[32][260];
    int bx = blockIdx.x, t = threadIdx.x;
    int d0 = (bx & 7) * 32, k0 = (bx >> 3) * 256;
    {
        int kk = t >> 3, dq = (t & 7) * 4;
        for (int i = 0; i < 8; ++i) {
            int kl = kk + i * 32;
            f16x4 v = *(const f16x4*)(dwT + (size_t)(k0 + kl) * DD + d0 + dq);
            tile[dq + 0][kl] = (float)v[0]; tile[dq + 1][kl] = (float)v[1];
            tile[dq + 2][kl] = (float)v[2]; tile[dq + 3][kl] = (float)v[3];
        }
    }
    __syncthreads();
    float sm = smoothed[k0 + t];
    for (int dv = 0; dv < 32; ++dv) {
        size_t o = (size_t)(d0 + dv) * KC + k0 + t;
        float dw = tile[dv][t];
        float ne = ema_embed[o] * 0.99f + 0.01f * dw;
        out_ema[o] = ne;
        out_embed[o] = ne / sm;
    }
}

// ---------- quantize gather (swizzled econv) + NCHW writeback ----------
__global__ __launch_bounds__(256, 2) void k_quantize_out(
    const int* __restrict__ idx, const f16* __restrict__ econv, float* __restrict__ out) {
    __shared__ float qv[256][68];
    __shared__ int li[64];
    int t = threadIdx.x;
    int n0 = blockIdx.x * 64;
    int b = n0 >> 10, h0 = (n0 >> 5) & 31;
    if (t < 64) li[t] = idx[n0 + t];
    __syncthreads();
    {
        int r = t >> 2, qt = t & 3;
        int k = li[r];
        int cb = k >> 7, C = k & 127;
        int p = qt ^ ((C >> 1) & 3);
        for (int kt = 0; kt < 8; ++kt) {
            size_t base = (((size_t)(cb * 8 + kt)) << 13) + C * 32 + p * 8;
            f16x8 hv = *(const f16x8*)&econv[base];
            f16x8 lv = *(const f16x8*)&econv[base + 4096];
            #pragma unroll
            for (int j = 0; j < 8; ++j)
                qv[kt * 32 + qt * 8 + j][r] = (float)hv[j] + (float)lv[j];
        }
    }
    __syncthreads();
    {
        int p = t >> 7, tt = t & 127;
        int wq = (tt & 7) * 4, d0 = tt >> 3;
        float* dst = out + (size_t)b * 262144 + (size_t)(h0 + p) * 32 + wq;
        for (int i = 0; i < 16; ++i) {
            int d = d0 + i * 16;
            float4 v = *(const float4*)&qv[d][p * 32 + wq];
            *(float4*)(dst + (size_t)d * 1024) = v;
        }
    }
}

extern "C" void kernel_launch(void* const* d_in, const int* in_sizes, int n_in,
                              void* d_out, int out_size, void* d_ws, size_t ws_size,
                              hipStream_t stream) {
    (void)in_sizes; (void)n_in; (void)out_size; (void)ws_size;
    const float* x            = (const float*)d_in[0];
    const float* embed        = (const float*)d_in[1];
    const float* cluster_size = (const float*)d_in[2];
    const float* ema_embed    = (const float*)d_in[3];
    float* out = (float*)d_out;
    char* ws = (char*)d_ws;

    // ---- workspace layout (46.8 MB total; round-1 proved >= 50.7 MB available) ----
    f16*   xconv    = (f16*)  (ws + 0);           // 33,554,432  (hi+lo: 32768*256*2*2B)
    f16*   econv    = (f16*)  (ws + 33554432);    //  8,388,608  (hi+lo: 8192*256*2*2B)
    float* enorm    = (float*)(ws + 41943040);    //     32,768
    float* smoothed = (float*)(ws + 41975808);    //     32,768
    int*   idx      = (int*)  (ws + 42008576);    //    131,072
    int*   order    = (int*)  (ws + 42139648);    //    131,072
    int*   cnt      = (int*)  (ws + 42270720);    //     32,768
    int*   cursor   = (int*)  (ws + 42303488);    //     32,768
    int*   offsets  = (int*)  (ws + 42336256);    //     32,768
    float* lossAcc  = (float*)(ws + 42369024);    //        256
    unsigned long long* rowmin = (unsigned long long*)(ws + 42369280); // 262,144
    f16*   dwT      = (f16*)  (ws + 42631424);    //  4,194,304 -> end 46,825,728

    float* out_q    = out;
    float* out_loss = out + 8388608;
    float* out_perp = out + 8388609;
    float* out_ncs  = out + 8388610;
    float* out_emb  = out + 8396802;
    float* out_ema  = out + 10493954;

    hipMemsetAsync(cnt, 0, 65536, stream);          // cnt + cursor adjacent
    hipMemsetAsync(lossAcc, 0, 8, stream);
    hipMemsetAsync(rowmin, 0xFF, 262144, stream);

    k_convert_x<<<512, 256, 0, stream>>>(x, xconv, lossAcc);
    k_convert_e<<<512, 256, 0, stream>>>(embed, econv);
    k_enorm<<<32, 256, 0, stream>>>(embed, enorm);
    k_argmin_mfma<<<dim3(256, 64), 256, 0, stream>>>(xconv, econv, enorm, rowmin);
    k_finalize<<<128, 256, 0, stream>>>(rowmin, idx, cnt, lossAcc);
    k_stats<<<1, 256, 0, stream>>>(cnt, cluster_size, lossAcc, out_ncs, out_loss, out_perp,
                                   smoothed, offsets);
    k_scatter<<<128, 256, 0, stream>>>(idx, offsets, cursor, order);
    k_dw<<<8192, 256, 0, stream>>>(cnt, offsets, order, xconv, dwT);
    k_update_embed<<<256, 256, 0, stream>>>(dwT, ema_embed, smoothed, out_emb, out_ema);
    k_quantize_out<<<512, 256, 0, stream>>>(idx, econv, out_q);
}